// Round 8
// baseline (2137.853 us; speedup 1.0000x reference)
//
#include <hip/hip_runtime.h>
#include <hip/hip_bf16.h>

typedef __hip_bfloat16 bf16;
typedef float f32x4 __attribute__((ext_vector_type(4)));
typedef __bf16 b16x8 __attribute__((ext_vector_type(8)));

constexpr int Lc = 12, Bc = 4, Nc = 512, Dc = 768, Hc = 12, DHc = 64, DFFc = 3072;
constexpr int QKVc = 3 * Dc;          // 2304
constexpr int Mrows = Bc * Nc;        // 2048
constexpr float SCALE = 0.125f;       // 1/sqrt(64)

__device__ __forceinline__ bf16 f2b(float x) { return __float2bfloat16(x); }

__device__ __forceinline__ void mfma_bf16(f32x4& d, b16x8 a, b16x8 b) {
  d = __builtin_amdgcn_mfma_f32_16x16x32_bf16(a, b, d, 0, 0, 0);
}

// async global->LDS, 16B per lane. LDS dest must be linear (wave base + lane*16).
__device__ __forceinline__ void gload16(const bf16* g, bf16* l) {
  __builtin_amdgcn_global_load_lds(
      (const __attribute__((address_space(1))) void*)g,
      (__attribute__((address_space(3))) void*)l, 16, 0, 0);
}

// ---------------------------------------------------------------------------
// Generic GEMM:  C[m][n] = sum_k A[m][k] * Bt[n][k]   (A, Bt bf16 row-major)
// 2-phase double-buffered K-loop (prefetch next tile before computing cur).
// MODE 0: outb = bf16(C)                      (qkv projection, no bias)
// MODE 1: outb = bf16(gelu(C + bias))         (ff1)
// MODE 2: xres += C + bias; SPLITK>1 -> atomicAdd partials (bias on slice 0)
// ---------------------------------------------------------------------------
template <int BM, int BN, int WM, int WN, int MODE, int SPLITK = 1>
__global__ __launch_bounds__(256) void gemm_bt(
    const bf16* __restrict__ Abase, const bf16* __restrict__ Btbase,
    const float* __restrict__ bias, float* __restrict__ xres,
    bf16* __restrict__ outb_,
    int M, int N, int K, int lda, int ldb, int ldc) {
  constexpr int MI = WM / 16, NI = WN / 16;
  constexpr int NWN = BN / WN;
  const int tid = threadIdx.x;
  const int lane = tid & 63, wave = tid >> 6;
  const int wm = (wave / NWN) * WM, wn = (wave % NWN) * WN;
  const int tm0 = blockIdx.x * BM, tn0 = blockIdx.y * BN;
  const int z = blockIdx.z;

  const bf16* A = Abase;
  const bf16* Bt = Btbase;
  bf16* outb = outb_;

  const int Kslice = K / SPLITK;
  const int kbase = (SPLITK > 1) ? z * Kslice : 0;

  __shared__ __align__(16) bf16 As[2][BM * 32];
  __shared__ __align__(16) bf16 Bs[2][BN * 32];

  f32x4 acc[MI][NI] = {};

  const int nt = Kslice >> 5;

  auto stage = [&](int buf, int k0) {
    #pragma unroll
    for (int rr = 0; rr < BM / 64; rr++) {
      int e = rr * 2048 + tid * 8;
      int r = e >> 5, kk = e & 31;
      gload16(A + (size_t)(tm0 + r) * lda + (kbase + k0 + kk), &As[buf][e]);
    }
    #pragma unroll
    for (int rr = 0; rr < BN / 64; rr++) {
      int e = rr * 2048 + tid * 8;
      int r = e >> 5, kk = e & 31;
      gload16(Bt + (size_t)(tn0 + r) * ldb + (kbase + k0 + kk), &Bs[buf][e]);
    }
  };

  stage(0, 0);
  __syncthreads();

  int cur = 0;
  for (int kt = 0; kt < nt; kt++) {
    if (kt + 1 < nt) stage(cur ^ 1, (kt + 1) * 32);

    b16x8 af[MI], bfr[NI];
    #pragma unroll
    for (int i = 0; i < MI; i++)
      af[i] = *(const b16x8*)(&As[cur][(wm + i * 16 + (lane & 15)) * 32 + (lane >> 4) * 8]);
    #pragma unroll
    for (int j = 0; j < NI; j++)
      bfr[j] = *(const b16x8*)(&Bs[cur][(wn + j * 16 + (lane & 15)) * 32 + (lane >> 4) * 8]);
    #pragma unroll
    for (int i = 0; i < MI; i++)
      #pragma unroll
      for (int j = 0; j < NI; j++)
        mfma_bf16(acc[i][j], af[i], bfr[j]);

    __syncthreads();
    cur ^= 1;
  }

  const int r0 = (lane >> 4) * 4;
  const int c0 = lane & 15;
  #pragma unroll
  for (int i = 0; i < MI; i++) {
    #pragma unroll
    for (int j = 0; j < NI; j++) {
      #pragma unroll
      for (int r = 0; r < 4; r++) {
        int row = tm0 + wm + i * 16 + r0 + r;
        int col = tn0 + wn + j * 16 + c0;
        float v = acc[i][j][r];
        if (MODE == 0) {
          outb[(size_t)row * ldc + col] = f2b(v);
        } else if (MODE == 1) {
          v += bias[col];
          float g = 0.5f * v * (1.0f + erff(v * 0.70710678118654752f));
          outb[(size_t)row * ldc + col] = f2b(g);
        } else if (MODE == 2) {
          if (SPLITK > 1) {
            if (z == 0) v += bias[col];
            atomicAdd(&xres[(size_t)row * ldc + col], v);
          } else {
            v += bias[col];
            xres[(size_t)row * ldc + col] += v;
          }
        }
      }
    }
  }
}

// ---------------------------------------------------------------------------
// Fused attention: QK^T*SCALE -> softmax (in-register) -> fp32 attn (d_out)
//                  -> P to LDS (bf16, kv-XOR swizzle) -> PV -> o (bf16).
// One block = 32 q-rows x all 512 kv for one (b,h).
// KV LDS buffer: K phase [512][72] padded; reused as V^T [64][512] swizzled.
// Swizzle col' = col ^ ((row&7)<<3): preserves 16B groups; makes the PV
// fragment reads 2-way (free) instead of 16-way bank conflicts.
// ---------------------------------------------------------------------------
__global__ __launch_bounds__(256) void fattn_k(const bf16* __restrict__ qkv,
                                               const bf16* __restrict__ vt,
                                               float* __restrict__ attn_f,
                                               bf16* __restrict__ o) {
  const int bh = blockIdx.y;
  const int b = bh / Hc, h = bh % Hc;
  const int n0 = blockIdx.x * 32;
  const int tid = threadIdx.x, lane = tid & 63, wave = tid >> 6;
  const int wn = wave * 128;

  constexpr int KP = 72;  // K-phase row pad (16B-aligned rows)
  __shared__ __align__(16) bf16 KV[512 * KP];   // K: [kv][72] | V^T: [64][512]
  __shared__ __align__(16) bf16 P[32 * 512];    // bf16 P, swizzled
  __shared__ float red[32][4];

  const bf16* qbase = qkv + (size_t)b * Nc * QKVc + h * DHc;  // Q cols
  const bf16* kbase = qbase + Dc;                             // K cols

  // stage K head: 512 x 64
  for (int e = tid * 8; e < 512 * 64; e += 2048) {
    int kv = e >> 6, c = e & 63;
    *(uint4*)(KV + kv * KP + c) = *(const uint4*)(kbase + (size_t)kv * QKVc + c);
  }
  b16x8 qf[2][2];  // [ks][i]
  #pragma unroll
  for (int ks = 0; ks < 2; ks++)
    #pragma unroll
    for (int i = 0; i < 2; i++)
      qf[ks][i] = *(const b16x8*)(qbase +
          (size_t)(n0 + i * 16 + (lane & 15)) * QKVc + ks * 32 + (lane >> 4) * 8);
  __syncthreads();

  // QK^T
  f32x4 acc[2][8] = {};
  #pragma unroll
  for (int ks = 0; ks < 2; ks++) {
    #pragma unroll
    for (int j = 0; j < 8; j++) {
      b16x8 kf = *(const b16x8*)(KV + (wn + j * 16 + (lane & 15)) * KP +
                                 ks * 32 + (lane >> 4) * 8);
      #pragma unroll
      for (int i = 0; i < 2; i++)
        mfma_bf16(acc[i][j], qf[ks][i], kf);
    }
  }

  // issue V^T global loads early: HBM/L2 latency hides under softmax VALU
  const bf16* vthead = vt + (size_t)bh * DHc * Nc;
  b16x8 vreg[16];
  #pragma unroll
  for (int r = 0; r < 16; r++)
    vreg[r] = *(const b16x8*)(vthead + r * 2048 + tid * 8);

  #pragma unroll
  for (int i = 0; i < 2; i++)
    #pragma unroll
    for (int j = 0; j < 8; j++)
      acc[i][j] *= SCALE;

  const int r0 = (lane >> 4) * 4, c0 = lane & 15;
  float rmax[2][4];
  #pragma unroll
  for (int i = 0; i < 2; i++)
    #pragma unroll
    for (int rr = 0; rr < 4; rr++) {
      float m = -1e30f;
      #pragma unroll
      for (int j = 0; j < 8; j++) m = fmaxf(m, acc[i][j][rr]);
      #pragma unroll
      for (int of = 1; of < 16; of <<= 1) m = fmaxf(m, __shfl_xor(m, of));
      rmax[i][rr] = m;
    }
  if (c0 == 0) {
    #pragma unroll
    for (int i = 0; i < 2; i++)
      #pragma unroll
      for (int rr = 0; rr < 4; rr++)
        red[i * 16 + r0 + rr][wave] = rmax[i][rr];
  }
  __syncthreads();   // also: all waves done reading KV (K phase)
  #pragma unroll
  for (int i = 0; i < 2; i++)
    #pragma unroll
    for (int rr = 0; rr < 4; rr++) {
      int r = i * 16 + r0 + rr;
      rmax[i][rr] = fmaxf(fmaxf(red[r][0], red[r][1]), fmaxf(red[r][2], red[r][3]));
    }
  __syncthreads();

  float rsum[2][4];
  #pragma unroll
  for (int i = 0; i < 2; i++)
    #pragma unroll
    for (int rr = 0; rr < 4; rr++) {
      float s = 0.f;
      #pragma unroll
      for (int j = 0; j < 8; j++) {
        float e = expf(acc[i][j][rr] - rmax[i][rr]);
        acc[i][j][rr] = e;
        s += e;
      }
      #pragma unroll
      for (int of = 1; of < 16; of <<= 1) s += __shfl_xor(s, of);
      rsum[i][rr] = s;
    }
  if (c0 == 0) {
    #pragma unroll
    for (int i = 0; i < 2; i++)
      #pragma unroll
      for (int rr = 0; rr < 4; rr++)
        red[i * 16 + r0 + rr][wave] = rsum[i][rr];
  }
  __syncthreads();
  #pragma unroll
  for (int i = 0; i < 2; i++)
    #pragma unroll
    for (int rr = 0; rr < 4; rr++) {
      int r = i * 16 + r0 + rr;
      rsum[i][rr] = 1.0f / (red[r][0] + red[r][1] + red[r][2] + red[r][3]);
    }

  // V^T into KV as [d][512] with kv swizzle (regs were loaded pre-softmax)
  #pragma unroll
  for (int r = 0; r < 16; r++) {
    int d = r * 4 + wave;
    int kvs = (lane * 8) ^ ((d & 7) << 3);
    *(uint4*)(KV + d * 512 + kvs) = *(uint4*)&vreg[r];
  }

  // fp32 attn out + bf16 P to LDS (swizzled)
  float* of32 = attn_f + (size_t)bh * Nc * Nc;
  #pragma unroll
  for (int i = 0; i < 2; i++)
    #pragma unroll
    for (int j = 0; j < 8; j++)
      #pragma unroll
      for (int rr = 0; rr < 4; rr++) {
        int rloc = i * 16 + r0 + rr;
        int col = wn + j * 16 + c0;
        float p = acc[i][j][rr] * rsum[i][rr];
        of32[(size_t)(n0 + rloc) * Nc + col] = p;
        P[rloc * 512 + (col ^ ((rloc & 7) << 3))] = f2b(p);
      }
  __syncthreads();

  // PV: each wave owns d-tile d0 = wave*16, q tiles i=0,1 ; K = 512
  f32x4 oacc[2] = {};
  #pragma unroll
  for (int ks = 0; ks < 16; ks++) {
    int kvb = ks * 32 + ((lane >> 4) << 3);
    int dd = wave * 16 + (lane & 15);
    b16x8 bf_ = *(const b16x8*)(KV + dd * 512 + (kvb ^ ((dd & 7) << 3)));
    #pragma unroll
    for (int i = 0; i < 2; i++) {
      int q = i * 16 + (lane & 15);
      b16x8 af_ = *(const b16x8*)(P + q * 512 + (kvb ^ ((q & 7) << 3)));
      mfma_bf16(oacc[i], af_, bf_);
    }
  }
  #pragma unroll
  for (int i = 0; i < 2; i++)
    #pragma unroll
    for (int r = 0; r < 4; r++) {
      int row = b * Nc + n0 + i * 16 + r0 + r;
      o[(size_t)row * Dc + h * DHc + wave * 16 + c0] = f2b(oacc[i][r]);
    }
}

// ---------------------------------------------------------------------------
// LayerNorm: per row of 768, fp32 in -> bf16 out
// ---------------------------------------------------------------------------
__global__ __launch_bounds__(256) void ln_k(const float* __restrict__ x,
                                            const float* __restrict__ s,
                                            const float* __restrict__ b,
                                            bf16* __restrict__ out) {
  const int row = blockIdx.x, tid = threadIdx.x;
  const float* xr = x + (size_t)row * Dc;
  float a0 = xr[tid], a1 = xr[tid + 256], a2 = xr[tid + 512];
  float sum = a0 + a1 + a2;
  float sq = a0 * a0 + a1 * a1 + a2 * a2;
  #pragma unroll
  for (int o = 32; o; o >>= 1) {
    sum += __shfl_down(sum, o);
    sq += __shfl_down(sq, o);
  }
  __shared__ float s1[4], s2[4];
  if ((tid & 63) == 0) { s1[tid >> 6] = sum; s2[tid >> 6] = sq; }
  __syncthreads();
  sum = s1[0] + s1[1] + s1[2] + s1[3];
  sq = s2[0] + s2[1] + s2[2] + s2[3];
  float m = sum * (1.0f / Dc);
  float var = sq * (1.0f / Dc) - m * m;
  float rs = rsqrtf(var + 1e-5f);
  bf16* orow = out + (size_t)row * Dc;
  orow[tid]       = f2b((a0 - m) * rs * s[tid]       + b[tid]);
  orow[tid + 256] = f2b((a1 - m) * rs * s[tid + 256] + b[tid + 256]);
  orow[tid + 512] = f2b((a2 - m) * rs * s[tid + 512] + b[tid + 512]);
}

// ---------------------------------------------------------------------------
// Batched weight transpose+convert for all 4 weights of one layer.
// ---------------------------------------------------------------------------
__global__ __launch_bounds__(256) void twb_all_k(
    const float* __restrict__ wqkv_l, const float* __restrict__ wo_l,
    const float* __restrict__ w1_l, const float* __restrict__ w2_l,
    bf16* __restrict__ wTq, bf16* __restrict__ wTo,
    bf16* __restrict__ wT1, bf16* __restrict__ wT2) {
  int f = blockIdx.x;
  const float* in;
  bf16* outp;
  int K, Nw, n0, k0;
  if (f < 432)       { in = wqkv_l; outp = wTq; K = Dc;   Nw = QKVc; n0 = (f % 36) * 64; k0 = (f / 36) * 64; }
  else if (f < 576)  { f -= 432;  in = wo_l; outp = wTo; K = Dc;   Nw = Dc;   n0 = (f % 12) * 64; k0 = (f / 12) * 64; }
  else if (f < 1152) { f -= 576;  in = w1_l; outp = wT1; K = Dc;   Nw = DFFc; n0 = (f % 48) * 64; k0 = (f / 48) * 64; }
  else               { f -= 1152; in = w2_l; outp = wT2; K = DFFc; Nw = Dc;   n0 = (f % 12) * 64; k0 = (f / 12) * 64; }

  __shared__ bf16 t[64][65];
  const int tx = threadIdx.x & 63, ty = threadIdx.x >> 6;
  #pragma unroll
  for (int kk = ty; kk < 64; kk += 4)
    t[tx][kk] = f2b(in[(size_t)(k0 + kk) * Nw + n0 + tx]);
  __syncthreads();
  #pragma unroll
  for (int nn = ty; nn < 64; nn += 4)
    outp[(size_t)(n0 + nn) * K + k0 + tx] = t[nn][tx];
}

// ---------------------------------------------------------------------------
// V transpose: vt[(b*H+h)*64 + d][n] = qkv[(b*512+n)][1536 + h*64 + d]
// ---------------------------------------------------------------------------
__global__ __launch_bounds__(256) void vtrans_k(const bf16* __restrict__ qkv,
                                                bf16* __restrict__ vt) {
  const int bh = blockIdx.z;
  const int b = bh / Hc, h = bh % Hc;
  const int n0 = blockIdx.x * 64;
  const bf16* src = qkv + (size_t)b * Nc * QKVc + 2 * Dc + h * DHc;
  __shared__ bf16 t[64][65];
  const int tx = threadIdx.x & 63, ty = threadIdx.x >> 6;
  #pragma unroll
  for (int nn = ty; nn < 64; nn += 4)
    t[tx][nn] = src[(size_t)(n0 + nn) * QKVc + tx];
  __syncthreads();
  bf16* dst = vt + (size_t)bh * DHc * Nc;
  #pragma unroll
  for (int dd = ty; dd < 64; dd += 4)
    dst[(size_t)dd * Nc + n0 + tx] = t[dd][tx];
}

// ---------------------------------------------------------------------------
extern "C" void kernel_launch(void* const* d_in, const int* in_sizes, int n_in,
                              void* d_out, int out_size, void* d_ws, size_t ws_size,
                              hipStream_t stream) {
  const float* x_in  = (const float*)d_in[0];
  const float* ln1_s = (const float*)d_in[1];
  const float* ln1_b = (const float*)d_in[2];
  const float* wqkv  = (const float*)d_in[3];
  const float* wo    = (const float*)d_in[4];
  const float* bo    = (const float*)d_in[5];
  const float* ln2_s = (const float*)d_in[6];
  const float* ln2_b = (const float*)d_in[7];
  const float* w1    = (const float*)d_in[8];
  const float* b1    = (const float*)d_in[9];
  const float* w2    = (const float*)d_in[10];
  const float* b2    = (const float*)d_in[11];
  float* out = (float*)d_out;   // fp32 (reference outputs are float32)

  // workspace carve-up (bytes)
  char* ws = (char*)d_ws;
  float* x      = (float*)(ws + 0);          //  6,291,456  fp32 [2048][768]
  bf16* h       = (bf16*)(ws + 6291456);     //  3,145,728
  bf16* qkv     = (bf16*)(ws + 9437184);     //  9,437,184
  bf16* o       = (bf16*)(ws + 18874368);    //  3,145,728
  bf16* ff      = (bf16*)(ws + 22020096);    // 12,582,912
  bf16* vt      = (bf16*)(ws + 34603008);    //  3,145,728
  bf16* wTq     = (bf16*)(ws + 37748736);    //  3,538,944  [2304][768]
  bf16* wTo     = (bf16*)(ws + 41287680);    //  1,179,648  [768][768]
  bf16* wT1     = (bf16*)(ws + 42467328);    //  4,718,592  [3072][768]
  bf16* wT2     = (bf16*)(ws + 47185920);    //  4,718,592  [768][3072]
  if (ws_size < (size_t)51904512) return;

  hipMemcpyAsync(x, x_in, (size_t)Mrows * Dc * sizeof(float),
                 hipMemcpyDeviceToDevice, stream);

  constexpr size_t ATTN_BASE = (size_t)Mrows * Dc;           // floats
  constexpr size_t ATTN_L = (size_t)Bc * Hc * Nc * Nc;       // floats

  for (int l = 0; l < Lc; l++) {
    float* attn_l = out + ATTN_BASE + (size_t)l * ATTN_L;    // fp32 slice

    twb_all_k<<<1728, 256, 0, stream>>>(
        wqkv + (size_t)l * Dc * QKVc, wo + (size_t)l * Dc * Dc,
        w1 + (size_t)l * Dc * DFFc, w2 + (size_t)l * DFFc * Dc,
        wTq, wTo, wT1, wT2);

    // --- attention ---
    ln_k<<<Mrows, 256, 0, stream>>>(x, ln1_s + l * Dc, ln1_b + l * Dc, h);
    gemm_bt<128, 128, 64, 64, 0><<<dim3(Mrows / 128, QKVc / 128, 1), 256, 0, stream>>>(
        h, wTq, nullptr, nullptr, qkv, Mrows, QKVc, Dc, Dc, Dc, QKVc);
    vtrans_k<<<dim3(Nc / 64, 1, Bc * Hc), 256, 0, stream>>>(qkv, vt);
    // fused QK^T + softmax + PV
    fattn_k<<<dim3(Nc / 32, Bc * Hc), 256, 0, stream>>>(qkv, vt, attn_l, o);
    // o-proj: split-K x2 -> 384 blocks
    gemm_bt<128, 64, 64, 32, 2, 2><<<dim3(Mrows / 128, Dc / 64, 2), 256, 0, stream>>>(
        o, wTo, bo + l * Dc, x, nullptr, Mrows, Dc, Dc, Dc, Dc, Dc);

    // --- feed-forward ---
    ln_k<<<Mrows, 256, 0, stream>>>(x, ln2_s + l * Dc, ln2_b + l * Dc, h);
    gemm_bt<128, 128, 64, 64, 1><<<dim3(Mrows / 128, DFFc / 128, 1), 256, 0, stream>>>(
        h, wT1, b1 + l * DFFc, nullptr, ff, Mrows, DFFc, Dc, Dc, Dc, DFFc);
    // ff2: split-K x4 -> 768 blocks
    gemm_bt<128, 64, 64, 32, 2, 4><<<dim3(Mrows / 128, Dc / 64, 4), 256, 0, stream>>>(
        ff, wT2, b2 + l * Dc, x, nullptr, Mrows, Dc, DFFc, DFFc, DFFc, Dc);
  }

  // final residual stream -> d_out (fp32)
  hipMemcpyAsync(out, x, (size_t)Mrows * Dc * sizeof(float),
                 hipMemcpyDeviceToDevice, stream);
}

// Round 9
// 1995.988 us; speedup vs baseline: 1.0711x; 1.0711x over previous
//
#include <hip/hip_runtime.h>
#include <hip/hip_bf16.h>

typedef __hip_bfloat16 bf16;
typedef float f32x4 __attribute__((ext_vector_type(4)));
typedef __bf16 b16x8 __attribute__((ext_vector_type(8)));

constexpr int Lc = 12, Bc = 4, Nc = 512, Dc = 768, Hc = 12, DHc = 64, DFFc = 3072;
constexpr int QKVc = 3 * Dc;          // 2304
constexpr int Mrows = Bc * Nc;        // 2048
constexpr float SCALE = 0.125f;       // 1/sqrt(64)

__device__ __forceinline__ bf16 f2b(float x) { return __float2bfloat16(x); }

__device__ __forceinline__ void mfma_bf16(f32x4& d, b16x8 a, b16x8 b) {
  d = __builtin_amdgcn_mfma_f32_16x16x32_bf16(a, b, d, 0, 0, 0);
}

// async global->LDS, 16B per lane. LDS dest linear (wave base + lane*16);
// any swizzle must be carried by the per-lane GLOBAL source address.
__device__ __forceinline__ void gload16(const bf16* g, bf16* l) {
  __builtin_amdgcn_global_load_lds(
      (const __attribute__((address_space(1))) void*)g,
      (__attribute__((address_space(3))) void*)l, 16, 0, 0);
}

// ---------------------------------------------------------------------------
// Generic GEMM:  C[m][n] = sum_k A[m][k] * Bt[n][k]   (A, Bt bf16 row-major)
// BK=64, 2-phase double-buffered. LDS tiles [row][64] with XOR chunk swizzle:
// LDS slot (row, c8) holds global chunk (c8 ^ (row&7)); ds_read applies the
// same XOR -> fragment reads are 2-way bank aliased (free). One barrier per
// 64-K step.
// MODE 0: outb = bf16(C); V-cols also scatter into vt  (qkv projection)
// MODE 1: outb = bf16(gelu(C + bias))                  (ff1)
// MODE 2: xres += C + bias; SPLITK>1 -> atomicAdd      (o-proj, ff2)
// ---------------------------------------------------------------------------
template <int BM, int BN, int WM, int WN, int MODE, int SPLITK = 1>
__global__ __launch_bounds__(256) void gemm_bt(
    const bf16* __restrict__ Abase, const bf16* __restrict__ Btbase,
    const float* __restrict__ bias, float* __restrict__ xres,
    bf16* __restrict__ outb, bf16* __restrict__ vtout,
    int M, int N, int K, int lda, int ldb, int ldc) {
  constexpr int MI = WM / 16, NI = WN / 16;
  constexpr int NWN = BN / WN;
  const int tid = threadIdx.x;
  const int lane = tid & 63, wave = tid >> 6;
  const int wm = (wave / NWN) * WM, wn = (wave % NWN) * WN;
  const int tm0 = blockIdx.x * BM, tn0 = blockIdx.y * BN;
  const int z = blockIdx.z;

  const bf16* A = Abase;
  const bf16* Bt = Btbase;

  const int Kslice = K / SPLITK;
  const int kbase = (SPLITK > 1) ? z * Kslice : 0;

  __shared__ __align__(16) bf16 As[2][BM * 64];
  __shared__ __align__(16) bf16 Bs[2][BN * 64];

  f32x4 acc[MI][NI] = {};

  const int nt = Kslice >> 6;  // 64-wide K steps

  auto stage = [&](int buf, int k0) {
    #pragma unroll
    for (int rr = 0; rr < BM / 32; rr++) {
      int idx = rr * 256 + tid;           // 16B-chunk id, linear in LDS
      int row = idx >> 3, c8 = idx & 7;
      int sc = ((c8 ^ (row & 7)) << 3);   // pre-swizzled source column
      gload16(A + (size_t)(tm0 + row) * lda + (kbase + k0 + sc), &As[buf][idx * 8]);
    }
    #pragma unroll
    for (int rr = 0; rr < BN / 32; rr++) {
      int idx = rr * 256 + tid;
      int row = idx >> 3, c8 = idx & 7;
      int sc = ((c8 ^ (row & 7)) << 3);
      gload16(Bt + (size_t)(tn0 + row) * ldb + (kbase + k0 + sc), &Bs[buf][idx * 8]);
    }
  };

  stage(0, 0);
  __syncthreads();

  int cur = 0;
  for (int kt = 0; kt < nt; kt++) {
    if (kt + 1 < nt) stage(cur ^ 1, (kt + 1) * 64);

    b16x8 af[2][MI], bfr[2][NI];
    #pragma unroll
    for (int ks = 0; ks < 2; ks++) {
      #pragma unroll
      for (int i = 0; i < MI; i++) {
        int r = wm + i * 16 + (lane & 15);
        int c = ks * 4 + (lane >> 4);
        af[ks][i] = *(const b16x8*)(&As[cur][r * 64 + ((c ^ (r & 7)) << 3)]);
      }
      #pragma unroll
      for (int j = 0; j < NI; j++) {
        int r = wn + j * 16 + (lane & 15);
        int c = ks * 4 + (lane >> 4);
        bfr[ks][j] = *(const b16x8*)(&Bs[cur][r * 64 + ((c ^ (r & 7)) << 3)]);
      }
    }
    #pragma unroll
    for (int ks = 0; ks < 2; ks++)
      #pragma unroll
      for (int i = 0; i < MI; i++)
        #pragma unroll
        for (int j = 0; j < NI; j++)
          mfma_bf16(acc[i][j], af[ks][i], bfr[ks][j]);

    __syncthreads();
    cur ^= 1;
  }

  // epilogue: D mapping col = lane&15, row = (lane>>4)*4 + reg
  const int r0 = (lane >> 4) * 4;
  const int c0 = lane & 15;
  #pragma unroll
  for (int i = 0; i < MI; i++) {
    #pragma unroll
    for (int j = 0; j < NI; j++) {
      #pragma unroll
      for (int r = 0; r < 4; r++) {
        int row = tm0 + wm + i * 16 + r0 + r;
        int col = tn0 + wn + j * 16 + c0;
        float v = acc[i][j][r];
        if (MODE == 0) {
          bf16 bv = f2b(v);
          outb[(size_t)row * ldc + col] = bv;
          if (col >= 2 * Dc) {  // V columns: also fill vt[bh][d][token]
            int cv = col - 2 * Dc;
            int bh = (row >> 9) * Hc + (cv >> 6);
            vtout[((size_t)bh * DHc + (cv & 63)) * Nc + (row & 511)] = bv;
          }
        } else if (MODE == 1) {
          v += bias[col];
          float g = 0.5f * v * (1.0f + erff(v * 0.70710678118654752f));
          outb[(size_t)row * ldc + col] = f2b(g);
        } else if (MODE == 2) {
          if (SPLITK > 1) {
            if (z == 0) v += bias[col];
            atomicAdd(&xres[(size_t)row * ldc + col], v);
          } else {
            v += bias[col];
            xres[(size_t)row * ldc + col] += v;
          }
        }
      }
    }
  }
}

// ---------------------------------------------------------------------------
// Fused attention: QK^T*SCALE -> softmax (in-register) -> fp32 attn (d_out)
//                  -> P to LDS (bf16, kv-XOR swizzle) -> PV -> o (bf16).
// One block = 32 q-rows x all 512 kv for one (b,h).
// ---------------------------------------------------------------------------
__global__ __launch_bounds__(256) void fattn_k(const bf16* __restrict__ qkv,
                                               const bf16* __restrict__ vt,
                                               float* __restrict__ attn_f,
                                               bf16* __restrict__ o) {
  const int bh = blockIdx.y;
  const int b = bh / Hc, h = bh % Hc;
  const int n0 = blockIdx.x * 32;
  const int tid = threadIdx.x, lane = tid & 63, wave = tid >> 6;
  const int wn = wave * 128;

  constexpr int KP = 72;
  __shared__ __align__(16) bf16 KV[512 * KP];   // K: [kv][72] | V^T: [64][512]
  __shared__ __align__(16) bf16 P[32 * 512];
  __shared__ float red[32][4];

  const bf16* qbase = qkv + (size_t)b * Nc * QKVc + h * DHc;
  const bf16* kbase = qbase + Dc;

  for (int e = tid * 8; e < 512 * 64; e += 2048) {
    int kv = e >> 6, c = e & 63;
    *(uint4*)(KV + kv * KP + c) = *(const uint4*)(kbase + (size_t)kv * QKVc + c);
  }
  b16x8 qf[2][2];
  #pragma unroll
  for (int ks = 0; ks < 2; ks++)
    #pragma unroll
    for (int i = 0; i < 2; i++)
      qf[ks][i] = *(const b16x8*)(qbase +
          (size_t)(n0 + i * 16 + (lane & 15)) * QKVc + ks * 32 + (lane >> 4) * 8);
  __syncthreads();

  f32x4 acc[2][8] = {};
  #pragma unroll
  for (int ks = 0; ks < 2; ks++) {
    #pragma unroll
    for (int j = 0; j < 8; j++) {
      b16x8 kf = *(const b16x8*)(KV + (wn + j * 16 + (lane & 15)) * KP +
                                 ks * 32 + (lane >> 4) * 8);
      #pragma unroll
      for (int i = 0; i < 2; i++)
        mfma_bf16(acc[i][j], qf[ks][i], kf);
    }
  }

  const bf16* vthead = vt + (size_t)bh * DHc * Nc;
  b16x8 vreg[16];
  #pragma unroll
  for (int r = 0; r < 16; r++)
    vreg[r] = *(const b16x8*)(vthead + r * 2048 + tid * 8);

  #pragma unroll
  for (int i = 0; i < 2; i++)
    #pragma unroll
    for (int j = 0; j < 8; j++)
      acc[i][j] *= SCALE;

  const int r0 = (lane >> 4) * 4, c0 = lane & 15;
  float rmax[2][4];
  #pragma unroll
  for (int i = 0; i < 2; i++)
    #pragma unroll
    for (int rr = 0; rr < 4; rr++) {
      float m = -1e30f;
      #pragma unroll
      for (int j = 0; j < 8; j++) m = fmaxf(m, acc[i][j][rr]);
      #pragma unroll
      for (int of = 1; of < 16; of <<= 1) m = fmaxf(m, __shfl_xor(m, of));
      rmax[i][rr] = m;
    }
  if (c0 == 0) {
    #pragma unroll
    for (int i = 0; i < 2; i++)
      #pragma unroll
      for (int rr = 0; rr < 4; rr++)
        red[i * 16 + r0 + rr][wave] = rmax[i][rr];
  }
  __syncthreads();
  #pragma unroll
  for (int i = 0; i < 2; i++)
    #pragma unroll
    for (int rr = 0; rr < 4; rr++) {
      int r = i * 16 + r0 + rr;
      rmax[i][rr] = fmaxf(fmaxf(red[r][0], red[r][1]), fmaxf(red[r][2], red[r][3]));
    }
  __syncthreads();

  float rsum[2][4];
  #pragma unroll
  for (int i = 0; i < 2; i++)
    #pragma unroll
    for (int rr = 0; rr < 4; rr++) {
      float s = 0.f;
      #pragma unroll
      for (int j = 0; j < 8; j++) {
        float e = expf(acc[i][j][rr] - rmax[i][rr]);
        acc[i][j][rr] = e;
        s += e;
      }
      #pragma unroll
      for (int of = 1; of < 16; of <<= 1) s += __shfl_xor(s, of);
      rsum[i][rr] = s;
    }
  if (c0 == 0) {
    #pragma unroll
    for (int i = 0; i < 2; i++)
      #pragma unroll
      for (int rr = 0; rr < 4; rr++)
        red[i * 16 + r0 + rr][wave] = rsum[i][rr];
  }
  __syncthreads();
  #pragma unroll
  for (int i = 0; i < 2; i++)
    #pragma unroll
    for (int rr = 0; rr < 4; rr++) {
      int r = i * 16 + r0 + rr;
      rsum[i][rr] = 1.0f / (red[r][0] + red[r][1] + red[r][2] + red[r][3]);
    }

  #pragma unroll
  for (int r = 0; r < 16; r++) {
    int d = r * 4 + wave;
    int kvs = (lane * 8) ^ ((d & 7) << 3);
    *(uint4*)(KV + d * 512 + kvs) = *(uint4*)&vreg[r];
  }

  float* of32 = attn_f + (size_t)bh * Nc * Nc;
  #pragma unroll
  for (int i = 0; i < 2; i++)
    #pragma unroll
    for (int j = 0; j < 8; j++)
      #pragma unroll
      for (int rr = 0; rr < 4; rr++) {
        int rloc = i * 16 + r0 + rr;
        int col = wn + j * 16 + c0;
        float p = acc[i][j][rr] * rsum[i][rr];
        of32[(size_t)(n0 + rloc) * Nc + col] = p;
        P[rloc * 512 + (col ^ ((rloc & 7) << 3))] = f2b(p);
      }
  __syncthreads();

  f32x4 oacc[2] = {};
  #pragma unroll
  for (int ks = 0; ks < 16; ks++) {
    int kvb = ks * 32 + ((lane >> 4) << 3);
    int dd = wave * 16 + (lane & 15);
    b16x8 bf_ = *(const b16x8*)(KV + dd * 512 + (kvb ^ ((dd & 7) << 3)));
    #pragma unroll
    for (int i = 0; i < 2; i++) {
      int q = i * 16 + (lane & 15);
      b16x8 af_ = *(const b16x8*)(P + q * 512 + (kvb ^ ((q & 7) << 3)));
      mfma_bf16(oacc[i], af_, bf_);
    }
  }
  #pragma unroll
  for (int i = 0; i < 2; i++)
    #pragma unroll
    for (int r = 0; r < 4; r++) {
      int row = b * Nc + n0 + i * 16 + r0 + r;
      o[(size_t)row * Dc + h * DHc + wave * 16 + c0] = f2b(oacc[i][r]);
    }
}

// ---------------------------------------------------------------------------
// Combined: ln1 (blocks [0,2048)) + all-4 weight transposes (blocks [2048,3776))
// ---------------------------------------------------------------------------
__global__ __launch_bounds__(256) void lntwb_k(
    const float* __restrict__ x, const float* __restrict__ s,
    const float* __restrict__ b, bf16* __restrict__ out,
    const float* __restrict__ wqkv_l, const float* __restrict__ wo_l,
    const float* __restrict__ w1_l, const float* __restrict__ w2_l,
    bf16* __restrict__ wTq, bf16* __restrict__ wTo,
    bf16* __restrict__ wT1, bf16* __restrict__ wT2) {
  __shared__ bf16 t[64][65];
  const int tid = threadIdx.x;
  if (blockIdx.x < 2048) {
    const int row = blockIdx.x;
    const float* xr = x + (size_t)row * Dc;
    float a0 = xr[tid], a1 = xr[tid + 256], a2 = xr[tid + 512];
    float sum = a0 + a1 + a2;
    float sq = a0 * a0 + a1 * a1 + a2 * a2;
    #pragma unroll
    for (int o = 32; o; o >>= 1) {
      sum += __shfl_down(sum, o);
      sq += __shfl_down(sq, o);
    }
    float* s1 = (float*)t;   // reuse LDS
    float* s2 = s1 + 4;
    if ((tid & 63) == 0) { s1[tid >> 6] = sum; s2[tid >> 6] = sq; }
    __syncthreads();
    sum = s1[0] + s1[1] + s1[2] + s1[3];
    sq = s2[0] + s2[1] + s2[2] + s2[3];
    float m = sum * (1.0f / Dc);
    float var = sq * (1.0f / Dc) - m * m;
    float rs = rsqrtf(var + 1e-5f);
    bf16* orow = out + (size_t)row * Dc;
    orow[tid]       = f2b((a0 - m) * rs * s[tid]       + b[tid]);
    orow[tid + 256] = f2b((a1 - m) * rs * s[tid + 256] + b[tid + 256]);
    orow[tid + 512] = f2b((a2 - m) * rs * s[tid + 512] + b[tid + 512]);
    return;
  }
  int f = blockIdx.x - 2048;
  const float* in;
  bf16* outp;
  int K, Nw, n0, k0;
  if (f < 432)       { in = wqkv_l; outp = wTq; K = Dc;   Nw = QKVc; n0 = (f % 36) * 64; k0 = (f / 36) * 64; }
  else if (f < 576)  { f -= 432;  in = wo_l; outp = wTo; K = Dc;   Nw = Dc;   n0 = (f % 12) * 64; k0 = (f / 12) * 64; }
  else if (f < 1152) { f -= 576;  in = w1_l; outp = wT1; K = Dc;   Nw = DFFc; n0 = (f % 48) * 64; k0 = (f / 48) * 64; }
  else               { f -= 1152; in = w2_l; outp = wT2; K = DFFc; Nw = Dc;   n0 = (f % 12) * 64; k0 = (f / 12) * 64; }
  const int tx = tid & 63, ty = tid >> 6;
  #pragma unroll
  for (int kk = ty; kk < 64; kk += 4)
    t[tx][kk] = f2b(in[(size_t)(k0 + kk) * Nw + n0 + tx]);
  __syncthreads();
  #pragma unroll
  for (int nn = ty; nn < 64; nn += 4)
    outp[(size_t)(n0 + nn) * K + k0 + tx] = t[nn][tx];
}

// ---------------------------------------------------------------------------
// LayerNorm (standalone, for ln2)
// ---------------------------------------------------------------------------
__global__ __launch_bounds__(256) void ln_k(const float* __restrict__ x,
                                            const float* __restrict__ s,
                                            const float* __restrict__ b,
                                            bf16* __restrict__ out) {
  const int row = blockIdx.x, tid = threadIdx.x;
  const float* xr = x + (size_t)row * Dc;
  float a0 = xr[tid], a1 = xr[tid + 256], a2 = xr[tid + 512];
  float sum = a0 + a1 + a2;
  float sq = a0 * a0 + a1 * a1 + a2 * a2;
  #pragma unroll
  for (int o = 32; o; o >>= 1) {
    sum += __shfl_down(sum, o);
    sq += __shfl_down(sq, o);
  }
  __shared__ float s1[4], s2[4];
  if ((tid & 63) == 0) { s1[tid >> 6] = sum; s2[tid >> 6] = sq; }
  __syncthreads();
  sum = s1[0] + s1[1] + s1[2] + s1[3];
  sq = s2[0] + s2[1] + s2[2] + s2[3];
  float m = sum * (1.0f / Dc);
  float var = sq * (1.0f / Dc) - m * m;
  float rs = rsqrtf(var + 1e-5f);
  bf16* orow = out + (size_t)row * Dc;
  orow[tid]       = f2b((a0 - m) * rs * s[tid]       + b[tid]);
  orow[tid + 256] = f2b((a1 - m) * rs * s[tid + 256] + b[tid + 256]);
  orow[tid + 512] = f2b((a2 - m) * rs * s[tid + 512] + b[tid + 512]);
}

// ---------------------------------------------------------------------------
extern "C" void kernel_launch(void* const* d_in, const int* in_sizes, int n_in,
                              void* d_out, int out_size, void* d_ws, size_t ws_size,
                              hipStream_t stream) {
  const float* x_in  = (const float*)d_in[0];
  const float* ln1_s = (const float*)d_in[1];
  const float* ln1_b = (const float*)d_in[2];
  const float* wqkv  = (const float*)d_in[3];
  const float* wo    = (const float*)d_in[4];
  const float* bo    = (const float*)d_in[5];
  const float* ln2_s = (const float*)d_in[6];
  const float* ln2_b = (const float*)d_in[7];
  const float* w1    = (const float*)d_in[8];
  const float* b1    = (const float*)d_in[9];
  const float* w2    = (const float*)d_in[10];
  const float* b2    = (const float*)d_in[11];
  float* out = (float*)d_out;   // fp32 (reference outputs are float32)

  // workspace carve-up (bytes)
  char* ws = (char*)d_ws;
  float* x      = (float*)(ws + 0);          //  6,291,456  fp32 [2048][768]
  bf16* h       = (bf16*)(ws + 6291456);     //  3,145,728
  bf16* qkv     = (bf16*)(ws + 9437184);     //  9,437,184
  bf16* o       = (bf16*)(ws + 18874368);    //  3,145,728
  bf16* ff      = (bf16*)(ws + 22020096);    // 12,582,912
  bf16* vt      = (bf16*)(ws + 34603008);    //  3,145,728
  bf16* wTq     = (bf16*)(ws + 37748736);    //  3,538,944  [2304][768]
  bf16* wTo     = (bf16*)(ws + 41287680);    //  1,179,648  [768][768]
  bf16* wT1     = (bf16*)(ws + 42467328);    //  4,718,592  [3072][768]
  bf16* wT2     = (bf16*)(ws + 47185920);    //  4,718,592  [768][3072]
  if (ws_size < (size_t)51904512) return;

  hipMemcpyAsync(x, x_in, (size_t)Mrows * Dc * sizeof(float),
                 hipMemcpyDeviceToDevice, stream);

  constexpr size_t ATTN_BASE = (size_t)Mrows * Dc;           // floats
  constexpr size_t ATTN_L = (size_t)Bc * Hc * Nc * Nc;       // floats

  for (int l = 0; l < Lc; l++) {
    float* attn_l = out + ATTN_BASE + (size_t)l * ATTN_L;

    // ln1 + all 4 weight transposes, one launch
    lntwb_k<<<3776, 256, 0, stream>>>(
        x, ln1_s + l * Dc, ln1_b + l * Dc, h,
        wqkv + (size_t)l * Dc * QKVc, wo + (size_t)l * Dc * Dc,
        w1 + (size_t)l * Dc * DFFc, w2 + (size_t)l * DFFc * Dc,
        wTq, wTo, wT1, wT2);

    // qkv projection (+ fused V-transpose for V columns)
    gemm_bt<128, 128, 64, 64, 0><<<dim3(Mrows / 128, QKVc / 128, 1), 256, 0, stream>>>(
        h, wTq, nullptr, nullptr, qkv, vt, Mrows, QKVc, Dc, Dc, Dc, QKVc);
    // fused QK^T + softmax + PV
    fattn_k<<<dim3(Nc / 32, Bc * Hc), 256, 0, stream>>>(qkv, vt, attn_l, o);
    // o-proj: split-K x2
    gemm_bt<128, 64, 64, 32, 2, 2><<<dim3(Mrows / 128, Dc / 64, 2), 256, 0, stream>>>(
        o, wTo, bo + l * Dc, x, nullptr, nullptr, Mrows, Dc, Dc, Dc, Dc, Dc);

    // --- feed-forward ---
    ln_k<<<Mrows, 256, 0, stream>>>(x, ln2_s + l * Dc, ln2_b + l * Dc, h);
    gemm_bt<128, 128, 64, 64, 1><<<dim3(Mrows / 128, DFFc / 128, 1), 256, 0, stream>>>(
        h, wT1, b1 + l * DFFc, nullptr, ff, nullptr, Mrows, DFFc, Dc, Dc, Dc, DFFc);
    // ff2: split-K x4
    gemm_bt<128, 64, 64, 32, 2, 4><<<dim3(Mrows / 128, Dc / 64, 4), 256, 0, stream>>>(
        ff, wT2, b2 + l * Dc, x, nullptr, nullptr, Mrows, Dc, DFFc, DFFc, DFFc, Dc);
  }

  hipMemcpyAsync(out, x, (size_t)Mrows * Dc * sizeof(float),
                 hipMemcpyDeviceToDevice, stream);
}

// Round 10
// 1820.762 us; speedup vs baseline: 1.1742x; 1.0962x over previous
//
#include <hip/hip_runtime.h>
#include <hip/hip_bf16.h>

typedef __hip_bfloat16 bf16;
typedef float f32x4 __attribute__((ext_vector_type(4)));
typedef __bf16 b16x8 __attribute__((ext_vector_type(8)));

constexpr int Lc = 12, Bc = 4, Nc = 512, Dc = 768, Hc = 12, DHc = 64, DFFc = 3072;
constexpr int QKVc = 3 * Dc;          // 2304
constexpr int Mrows = Bc * Nc;        // 2048
constexpr float SCALE = 0.125f;       // 1/sqrt(64)

__device__ __forceinline__ bf16 f2b(float x) { return __float2bfloat16(x); }

__device__ __forceinline__ void mfma_bf16(f32x4& d, b16x8 a, b16x8 b) {
  d = __builtin_amdgcn_mfma_f32_16x16x32_bf16(a, b, d, 0, 0, 0);
}

// async global->LDS, 16B per lane. LDS dest linear (wave base + lane*16);
// any swizzle must be carried by the per-lane GLOBAL source address.
__device__ __forceinline__ void gload16(const bf16* g, bf16* l) {
  __builtin_amdgcn_global_load_lds(
      (const __attribute__((address_space(1))) void*)g,
      (__attribute__((address_space(3))) void*)l, 16, 0, 0);
}

// ---------------------------------------------------------------------------
// Generic GEMM:  C[m][n] = sum_k A[m][k] * Bt[n][k]   (A, Bt bf16 row-major)
// BK=64, 2-phase double-buffered, XOR chunk swizzle (both-sides: pre-swizzled
// global source for the linear global_load_lds dest + swizzled ds_read).
// MODE 0: outb = bf16(C); V-cols also scatter into vt  (qkv projection)
// MODE 1: outb = bf16(gelu(C + bias))                  (ff1)
// MODE 2: xres += C + bias; SPLITK>1 -> atomicAdd      (o-proj, ff2)
// ---------------------------------------------------------------------------
template <int BM, int BN, int WM, int WN, int MODE, int SPLITK = 1>
__global__ __launch_bounds__(256) void gemm_bt(
    const bf16* __restrict__ Abase, const bf16* __restrict__ Btbase,
    const float* __restrict__ bias, float* __restrict__ xres,
    bf16* __restrict__ outb, bf16* __restrict__ vtout,
    int M, int N, int K, int lda, int ldb, int ldc) {
  constexpr int MI = WM / 16, NI = WN / 16;
  constexpr int NWN = BN / WN;
  const int tid = threadIdx.x;
  const int lane = tid & 63, wave = tid >> 6;
  const int wm = (wave / NWN) * WM, wn = (wave % NWN) * WN;
  const int tm0 = blockIdx.x * BM, tn0 = blockIdx.y * BN;
  const int z = blockIdx.z;

  const bf16* A = Abase;
  const bf16* Bt = Btbase;

  const int Kslice = K / SPLITK;
  const int kbase = (SPLITK > 1) ? z * Kslice : 0;

  __shared__ __align__(16) bf16 As[2][BM * 64];
  __shared__ __align__(16) bf16 Bs[2][BN * 64];

  f32x4 acc[MI][NI] = {};

  const int nt = Kslice >> 6;  // 64-wide K steps

  auto stage = [&](int buf, int k0) {
    #pragma unroll
    for (int rr = 0; rr < BM / 32; rr++) {
      int idx = rr * 256 + tid;           // 16B-chunk id, linear in LDS
      int row = idx >> 3, c8 = idx & 7;
      int sc = ((c8 ^ (row & 7)) << 3);   // pre-swizzled source column
      gload16(A + (size_t)(tm0 + row) * lda + (kbase + k0 + sc), &As[buf][idx * 8]);
    }
    #pragma unroll
    for (int rr = 0; rr < BN / 32; rr++) {
      int idx = rr * 256 + tid;
      int row = idx >> 3, c8 = idx & 7;
      int sc = ((c8 ^ (row & 7)) << 3);
      gload16(Bt + (size_t)(tn0 + row) * ldb + (kbase + k0 + sc), &Bs[buf][idx * 8]);
    }
  };

  stage(0, 0);
  __syncthreads();

  int cur = 0;
  for (int kt = 0; kt < nt; kt++) {
    if (kt + 1 < nt) stage(cur ^ 1, (kt + 1) * 64);

    b16x8 af[2][MI], bfr[2][NI];
    #pragma unroll
    for (int ks = 0; ks < 2; ks++) {
      #pragma unroll
      for (int i = 0; i < MI; i++) {
        int r = wm + i * 16 + (lane & 15);
        int c = ks * 4 + (lane >> 4);
        af[ks][i] = *(const b16x8*)(&As[cur][r * 64 + ((c ^ (r & 7)) << 3)]);
      }
      #pragma unroll
      for (int j = 0; j < NI; j++) {
        int r = wn + j * 16 + (lane & 15);
        int c = ks * 4 + (lane >> 4);
        bfr[ks][j] = *(const b16x8*)(&Bs[cur][r * 64 + ((c ^ (r & 7)) << 3)]);
      }
    }
    #pragma unroll
    for (int ks = 0; ks < 2; ks++)
      #pragma unroll
      for (int i = 0; i < MI; i++)
        #pragma unroll
        for (int j = 0; j < NI; j++)
          mfma_bf16(acc[i][j], af[ks][i], bfr[ks][j]);

    __syncthreads();
    cur ^= 1;
  }

  // epilogue: D mapping col = lane&15, row = (lane>>4)*4 + reg
  const int r0 = (lane >> 4) * 4;
  const int c0 = lane & 15;
  #pragma unroll
  for (int i = 0; i < MI; i++) {
    #pragma unroll
    for (int j = 0; j < NI; j++) {
      #pragma unroll
      for (int r = 0; r < 4; r++) {
        int row = tm0 + wm + i * 16 + r0 + r;
        int col = tn0 + wn + j * 16 + c0;
        float v = acc[i][j][r];
        if (MODE == 0) {
          bf16 bv = f2b(v);
          outb[(size_t)row * ldc + col] = bv;
          if (col >= 2 * Dc) {  // V columns: also fill vt[bh][d][token]
            int cv = col - 2 * Dc;
            int bh = (row >> 9) * Hc + (cv >> 6);
            vtout[((size_t)bh * DHc + (cv & 63)) * Nc + (row & 511)] = bv;
          }
        } else if (MODE == 1) {
          v += bias[col];
          float g = 0.5f * v * (1.0f + erff(v * 0.70710678118654752f));
          outb[(size_t)row * ldc + col] = f2b(g);
        } else if (MODE == 2) {
          if (SPLITK > 1) {
            if (z == 0) v += bias[col];
            atomicAdd(&xres[(size_t)row * ldc + col], v);
          } else {
            v += bias[col];
            xres[(size_t)row * ldc + col] += v;
          }
        }
      }
    }
  }
}

// ---------------------------------------------------------------------------
// Fused attention v2: K and V^T are L2-resident (64 KB/head) -> read
// fragments DIRECTLY from global (no LDS staging; m169 lesson). LDS only
// holds P (32 KB, kv-XOR swizzled) -> ~4 blocks/CU instead of 1.
// One block = 32 q-rows x all 512 kv for one (b,h).
// ---------------------------------------------------------------------------
__global__ __launch_bounds__(256) void fattn_k(const bf16* __restrict__ qkv,
                                               const bf16* __restrict__ vt,
                                               float* __restrict__ attn_f,
                                               bf16* __restrict__ o) {
  const int bh = blockIdx.y;
  const int b = bh / Hc, h = bh % Hc;
  const int n0 = blockIdx.x * 32;
  const int tid = threadIdx.x, lane = tid & 63, wave = tid >> 6;
  const int wn = wave * 128;

  __shared__ __align__(16) bf16 P[32 * 512];
  __shared__ float red[32][4];

  const bf16* qbase = qkv + (size_t)b * Nc * QKVc + h * DHc;
  const bf16* kbase = qbase + Dc;
  const bf16* vthead = vt + (size_t)bh * DHc * Nc;

  // Q fragments from global
  b16x8 qf[2][2];
  #pragma unroll
  for (int ks = 0; ks < 2; ks++)
    #pragma unroll
    for (int i = 0; i < 2; i++)
      qf[ks][i] = *(const b16x8*)(qbase +
          (size_t)(n0 + i * 16 + (lane & 15)) * QKVc + ks * 32 + (lane >> 4) * 8);

  // QK^T: K fragments direct from global (L2)
  f32x4 acc[2][8] = {};
  #pragma unroll
  for (int ks = 0; ks < 2; ks++) {
    #pragma unroll
    for (int j = 0; j < 8; j++) {
      b16x8 kf = *(const b16x8*)(kbase +
          (size_t)(wn + j * 16 + (lane & 15)) * QKVc + ks * 32 + (lane >> 4) * 8);
      #pragma unroll
      for (int i = 0; i < 2; i++)
        mfma_bf16(acc[i][j], qf[ks][i], kf);
    }
  }

  #pragma unroll
  for (int i = 0; i < 2; i++)
    #pragma unroll
    for (int j = 0; j < 8; j++)
      acc[i][j] *= SCALE;

  const int r0 = (lane >> 4) * 4, c0 = lane & 15;
  float rmax[2][4];
  #pragma unroll
  for (int i = 0; i < 2; i++)
    #pragma unroll
    for (int rr = 0; rr < 4; rr++) {
      float m = -1e30f;
      #pragma unroll
      for (int j = 0; j < 8; j++) m = fmaxf(m, acc[i][j][rr]);
      #pragma unroll
      for (int of = 1; of < 16; of <<= 1) m = fmaxf(m, __shfl_xor(m, of));
      rmax[i][rr] = m;
    }
  if (c0 == 0) {
    #pragma unroll
    for (int i = 0; i < 2; i++)
      #pragma unroll
      for (int rr = 0; rr < 4; rr++)
        red[i * 16 + r0 + rr][wave] = rmax[i][rr];
  }
  __syncthreads();
  #pragma unroll
  for (int i = 0; i < 2; i++)
    #pragma unroll
    for (int rr = 0; rr < 4; rr++) {
      int r = i * 16 + r0 + rr;
      rmax[i][rr] = fmaxf(fmaxf(red[r][0], red[r][1]), fmaxf(red[r][2], red[r][3]));
    }
  __syncthreads();

  float rsum[2][4];
  #pragma unroll
  for (int i = 0; i < 2; i++)
    #pragma unroll
    for (int rr = 0; rr < 4; rr++) {
      float s = 0.f;
      #pragma unroll
      for (int j = 0; j < 8; j++) {
        float e = expf(acc[i][j][rr] - rmax[i][rr]);
        acc[i][j][rr] = e;
        s += e;
      }
      #pragma unroll
      for (int of = 1; of < 16; of <<= 1) s += __shfl_xor(s, of);
      rsum[i][rr] = s;
    }
  if (c0 == 0) {
    #pragma unroll
    for (int i = 0; i < 2; i++)
      #pragma unroll
      for (int rr = 0; rr < 4; rr++)
        red[i * 16 + r0 + rr][wave] = rsum[i][rr];
  }
  __syncthreads();
  #pragma unroll
  for (int i = 0; i < 2; i++)
    #pragma unroll
    for (int rr = 0; rr < 4; rr++) {
      int r = i * 16 + r0 + rr;
      rsum[i][rr] = 1.0f / (red[r][0] + red[r][1] + red[r][2] + red[r][3]);
    }

  // fp32 attn out + bf16 P to LDS (swizzled)
  float* of32 = attn_f + (size_t)bh * Nc * Nc;
  #pragma unroll
  for (int i = 0; i < 2; i++)
    #pragma unroll
    for (int j = 0; j < 8; j++)
      #pragma unroll
      for (int rr = 0; rr < 4; rr++) {
        int rloc = i * 16 + r0 + rr;
        int col = wn + j * 16 + c0;
        float p = acc[i][j][rr] * rsum[i][rr];
        of32[(size_t)(n0 + rloc) * Nc + col] = p;
        P[rloc * 512 + (col ^ ((rloc & 7) << 3))] = f2b(p);
      }
  __syncthreads();

  // PV: V^T fragments direct from global (L2); P from swizzled LDS
  f32x4 oacc[2] = {};
  const int dd = wave * 16 + (lane & 15);
  #pragma unroll
  for (int ks = 0; ks < 16; ks++) {
    int kvb = ks * 32 + ((lane >> 4) << 3);
    b16x8 bf_ = *(const b16x8*)(vthead + (size_t)dd * 512 + kvb);
    #pragma unroll
    for (int i = 0; i < 2; i++) {
      int q = i * 16 + (lane & 15);
      b16x8 af_ = *(const b16x8*)(P + q * 512 + (kvb ^ ((q & 7) << 3)));
      mfma_bf16(oacc[i], af_, bf_);
    }
  }
  #pragma unroll
  for (int i = 0; i < 2; i++)
    #pragma unroll
    for (int r = 0; r < 4; r++) {
      int row = b * Nc + n0 + i * 16 + r0 + r;
      o[(size_t)row * Dc + h * DHc + wave * 16 + c0] = f2b(oacc[i][r]);
    }
}

// ---------------------------------------------------------------------------
// Combined: ln1 (blocks [0,2048)) + all-4 weight transposes (blocks [2048,3776))
// ---------------------------------------------------------------------------
__global__ __launch_bounds__(256) void lntwb_k(
    const float* __restrict__ x, const float* __restrict__ s,
    const float* __restrict__ b, bf16* __restrict__ out,
    const float* __restrict__ wqkv_l, const float* __restrict__ wo_l,
    const float* __restrict__ w1_l, const float* __restrict__ w2_l,
    bf16* __restrict__ wTq, bf16* __restrict__ wTo,
    bf16* __restrict__ wT1, bf16* __restrict__ wT2) {
  __shared__ bf16 t[64][65];
  const int tid = threadIdx.x;
  if (blockIdx.x < 2048) {
    const int row = blockIdx.x;
    const float* xr = x + (size_t)row * Dc;
    float a0 = xr[tid], a1 = xr[tid + 256], a2 = xr[tid + 512];
    float sum = a0 + a1 + a2;
    float sq = a0 * a0 + a1 * a1 + a2 * a2;
    #pragma unroll
    for (int o = 32; o; o >>= 1) {
      sum += __shfl_down(sum, o);
      sq += __shfl_down(sq, o);
    }
    float* s1 = (float*)t;   // reuse LDS
    float* s2 = s1 + 4;
    if ((tid & 63) == 0) { s1[tid >> 6] = sum; s2[tid >> 6] = sq; }
    __syncthreads();
    sum = s1[0] + s1[1] + s1[2] + s1[3];
    sq = s2[0] + s2[1] + s2[2] + s2[3];
    float m = sum * (1.0f / Dc);
    float var = sq * (1.0f / Dc) - m * m;
    float rs = rsqrtf(var + 1e-5f);
    bf16* orow = out + (size_t)row * Dc;
    orow[tid]       = f2b((a0 - m) * rs * s[tid]       + b[tid]);
    orow[tid + 256] = f2b((a1 - m) * rs * s[tid + 256] + b[tid + 256]);
    orow[tid + 512] = f2b((a2 - m) * rs * s[tid + 512] + b[tid + 512]);
    return;
  }
  int f = blockIdx.x - 2048;
  const float* in;
  bf16* outp;
  int K, Nw, n0, k0;
  if (f < 432)       { in = wqkv_l; outp = wTq; K = Dc;   Nw = QKVc; n0 = (f % 36) * 64; k0 = (f / 36) * 64; }
  else if (f < 576)  { f -= 432;  in = wo_l; outp = wTo; K = Dc;   Nw = Dc;   n0 = (f % 12) * 64; k0 = (f / 12) * 64; }
  else if (f < 1152) { f -= 576;  in = w1_l; outp = wT1; K = Dc;   Nw = DFFc; n0 = (f % 48) * 64; k0 = (f / 48) * 64; }
  else               { f -= 1152; in = w2_l; outp = wT2; K = DFFc; Nw = Dc;   n0 = (f % 12) * 64; k0 = (f / 12) * 64; }
  const int tx = tid & 63, ty = tid >> 6;
  #pragma unroll
  for (int kk = ty; kk < 64; kk += 4)
    t[tx][kk] = f2b(in[(size_t)(k0 + kk) * Nw + n0 + tx]);
  __syncthreads();
  #pragma unroll
  for (int nn = ty; nn < 64; nn += 4)
    outp[(size_t)(n0 + nn) * K + k0 + tx] = t[nn][tx];
}

// ---------------------------------------------------------------------------
// LayerNorm (standalone, for ln2)
// ---------------------------------------------------------------------------
__global__ __launch_bounds__(256) void ln_k(const float* __restrict__ x,
                                            const float* __restrict__ s,
                                            const float* __restrict__ b,
                                            bf16* __restrict__ out) {
  const int row = blockIdx.x, tid = threadIdx.x;
  const float* xr = x + (size_t)row * Dc;
  float a0 = xr[tid], a1 = xr[tid + 256], a2 = xr[tid + 512];
  float sum = a0 + a1 + a2;
  float sq = a0 * a0 + a1 * a1 + a2 * a2;
  #pragma unroll
  for (int o = 32; o; o >>= 1) {
    sum += __shfl_down(sum, o);
    sq += __shfl_down(sq, o);
  }
  __shared__ float s1[4], s2[4];
  if ((tid & 63) == 0) { s1[tid >> 6] = sum; s2[tid >> 6] = sq; }
  __syncthreads();
  sum = s1[0] + s1[1] + s1[2] + s1[3];
  sq = s2[0] + s2[1] + s2[2] + s2[3];
  float m = sum * (1.0f / Dc);
  float var = sq * (1.0f / Dc) - m * m;
  float rs = rsqrtf(var + 1e-5f);
  bf16* orow = out + (size_t)row * Dc;
  orow[tid]       = f2b((a0 - m) * rs * s[tid]       + b[tid]);
  orow[tid + 256] = f2b((a1 - m) * rs * s[tid + 256] + b[tid + 256]);
  orow[tid + 512] = f2b((a2 - m) * rs * s[tid + 512] + b[tid + 512]);
}

// ---------------------------------------------------------------------------
extern "C" void kernel_launch(void* const* d_in, const int* in_sizes, int n_in,
                              void* d_out, int out_size, void* d_ws, size_t ws_size,
                              hipStream_t stream) {
  const float* x_in  = (const float*)d_in[0];
  const float* ln1_s = (const float*)d_in[1];
  const float* ln1_b = (const float*)d_in[2];
  const float* wqkv  = (const float*)d_in[3];
  const float* wo    = (const float*)d_in[4];
  const float* bo    = (const float*)d_in[5];
  const float* ln2_s = (const float*)d_in[6];
  const float* ln2_b = (const float*)d_in[7];
  const float* w1    = (const float*)d_in[8];
  const float* b1    = (const float*)d_in[9];
  const float* w2    = (const float*)d_in[10];
  const float* b2    = (const float*)d_in[11];
  float* out = (float*)d_out;   // fp32 (reference outputs are float32)

  // workspace carve-up (bytes)
  char* ws = (char*)d_ws;
  float* x      = (float*)(ws + 0);          //  6,291,456  fp32 [2048][768]
  bf16* h       = (bf16*)(ws + 6291456);     //  3,145,728
  bf16* qkv     = (bf16*)(ws + 9437184);     //  9,437,184
  bf16* o       = (bf16*)(ws + 18874368);    //  3,145,728
  bf16* ff      = (bf16*)(ws + 22020096);    // 12,582,912
  bf16* vt      = (bf16*)(ws + 34603008);    //  3,145,728
  bf16* wTq     = (bf16*)(ws + 37748736);    //  3,538,944  [2304][768]
  bf16* wTo     = (bf16*)(ws + 41287680);    //  1,179,648  [768][768]
  bf16* wT1     = (bf16*)(ws + 42467328);    //  4,718,592  [3072][768]
  bf16* wT2     = (bf16*)(ws + 47185920);    //  4,718,592  [768][3072]
  if (ws_size < (size_t)51904512) return;

  hipMemcpyAsync(x, x_in, (size_t)Mrows * Dc * sizeof(float),
                 hipMemcpyDeviceToDevice, stream);

  constexpr size_t ATTN_BASE = (size_t)Mrows * Dc;           // floats
  constexpr size_t ATTN_L = (size_t)Bc * Hc * Nc * Nc;       // floats

  for (int l = 0; l < Lc; l++) {
    float* attn_l = out + ATTN_BASE + (size_t)l * ATTN_L;

    // ln1 + all 4 weight transposes, one launch
    lntwb_k<<<3776, 256, 0, stream>>>(
        x, ln1_s + l * Dc, ln1_b + l * Dc, h,
        wqkv + (size_t)l * Dc * QKVc, wo + (size_t)l * Dc * Dc,
        w1 + (size_t)l * Dc * DFFc, w2 + (size_t)l * DFFc * Dc,
        wTq, wTo, wT1, wT2);

    // qkv projection (+ fused V-transpose for V columns)
    gemm_bt<128, 128, 64, 64, 0><<<dim3(Mrows / 128, QKVc / 128, 1), 256, 0, stream>>>(
        h, wTq, nullptr, nullptr, qkv, vt, Mrows, QKVc, Dc, Dc, Dc, QKVc);
    // fused QK^T + softmax + PV (K/V direct from L2)
    fattn_k<<<dim3(Nc / 32, Bc * Hc), 256, 0, stream>>>(qkv, vt, attn_l, o);
    // o-proj: split-K x2
    gemm_bt<128, 64, 64, 32, 2, 2><<<dim3(Mrows / 128, Dc / 64, 2), 256, 0, stream>>>(
        o, wTo, bo + l * Dc, x, nullptr, nullptr, Mrows, Dc, Dc, Dc, Dc, Dc);

    // --- feed-forward ---
    ln_k<<<Mrows, 256, 0, stream>>>(x, ln2_s + l * Dc, ln2_b + l * Dc, h);
    gemm_bt<128, 128, 64, 64, 1><<<dim3(Mrows / 128, DFFc / 128, 1), 256, 0, stream>>>(
        h, wT1, b1 + l * DFFc, nullptr, ff, nullptr, Mrows, DFFc, Dc, Dc, Dc, DFFc);
    // ff2: split-K x4
    gemm_bt<128, 64, 64, 32, 2, 4><<<dim3(Mrows / 128, Dc / 64, 4), 256, 0, stream>>>(
        ff, wT2, b2 + l * Dc, x, nullptr, nullptr, Mrows, Dc, DFFc, DFFc, DFFc, Dc);
  }

  hipMemcpyAsync(out, x, (size_t)Mrows * Dc * sizeof(float),
                 hipMemcpyDeviceToDevice, stream);
}